// Round 1
// baseline (274.468 us; speedup 1.0000x reference)
//
#include <hip/hip_runtime.h>

// KGAN forward loss on MI355X.
// Decomposition: block = batch row b (1024 blocks x 1024 threads),
// wave = group g (16), lane = dim d (64).
// Collapses: rv -> rdotv[17] per block; attn MLP -> u = W1@w2 per hop;
// softmax over 32 consecutive d == half-wave reduce.

#define BATCH 1024
#define G     16
#define NMEM  32
#define DIM   64
#define NREL  17

__device__ __forceinline__ float fullReduceSum(float v) {
#pragma unroll
    for (int m = 1; m < 64; m <<= 1) v += __shfl_xor(v, m, 64);
    return v;
}
__device__ __forceinline__ float halfReduceSum(float v) {
#pragma unroll
    for (int m = 1; m < 32; m <<= 1) v += __shfl_xor(v, m, 64);
    return v;
}
__device__ __forceinline__ float halfReduceMax(float v) {
#pragma unroll
    for (int m = 1; m < 32; m <<= 1) v = fmaxf(v, __shfl_xor(v, m, 64));
    return v;
}

// ws layout: acc double[4] at offset 0 (loss_sum, kge_sum, l2_sum);
// u float[2*64] at offset 64.
__global__ void kgan_prep(const float* __restrict__ attn_w1,
                          const float* __restrict__ attn_w2,
                          float* __restrict__ u, double* __restrict__ acc) {
    int t = threadIdx.x;            // 0..127
    if (t < 4) acc[t] = 0.0;
    int hop = t >> 6, d = t & 63;
    float s = 0.f;
#pragma unroll
    for (int e = 0; e < DIM; ++e)
        s = fmaf(attn_w1[(hop * DIM + d) * DIM + e], attn_w2[hop * DIM + e], s);
    u[t] = s;
}

__launch_bounds__(1024, 2)
__global__ void kgan_main(const int* __restrict__ pos_items,
                          const int* __restrict__ neg_items,
                          const int* __restrict__ mem_h,
                          const int* __restrict__ mem_r,
                          const int* __restrict__ mem_t,
                          const float* __restrict__ ent,
                          const float* __restrict__ rel,
                          const float* __restrict__ Tm,
                          const float* __restrict__ u,
                          double* __restrict__ acc) {
    const int b    = blockIdx.x;
    const int tid  = threadIdx.x;
    const int g    = tid >> 6;
    const int lane = tid & 63;

    __shared__ float rel_lds[NREL][DIM];
    __shared__ float rdotv[NREL];
    __shared__ float rsq[NREL];
    __shared__ float a_lds[G];
    __shared__ float o_lds[G][DIM];
    __shared__ float red_kge[G];
    __shared__ float red_l2[G];
    __shared__ float y_lds[DIM];

    // stage relation table (17*64 = 1088 floats)
    for (int i = tid; i < NREL * DIM; i += 1024)
        ((float*)rel_lds)[i] = rel[i];

    const float v = ent[(size_t)pos_items[b] * DIM + lane];
    __syncthreads();

    // per-block precompute: rdotv[rel] = dot(rel_row, v), rsq[rel] = ||rel_row||^2
    for (int rr = g; rr < NREL; rr += G) {
        float rd = rel_lds[rr][lane];
        float s1 = fullReduceSum(rd * v);
        float s2 = fullReduceSum(rd * rd);
        if (lane == 0) { rdotv[rr] = s1; rsq[rr] = s2; }
    }
    __syncthreads();

    float kge_acc = 0.f, l2_acc = 0.f, l2r_acc = 0.f;
    float y0 = 0.f;   // wave 0: accumulated y_d = sum_hop o_h
    float x1 = 0.f;   // wave 0: v + o_h(last hop)

    for (int hop = 0; hop < 2; ++hop) {
        const int base = ((hop * BATCH + b) * G + g) * NMEM;
        // lanes 0..31 hold h-indices (m=lane), lanes 32..63 hold t-indices
        int idx_ht = (lane < NMEM) ? mem_h[base + lane] : mem_t[base + lane - NMEM];
        int idx_r  = (lane < NMEM) ? mem_r[base + lane] : 0;

        float o_d = 0.f;
        for (int m = 0; m < NMEM; ++m) {
            int ih = __shfl(idx_ht, m, 64);
            int it = __shfl(idx_ht, m + NMEM, 64);
            int ir = __shfl(idx_r, m, 64);

            float h = ent[(size_t)ih * DIM + lane];
            float t = ent[(size_t)it * DIM + lane];
            float r = rel_lds[ir][lane];

            // softmax over 32 consecutive d within (b,g,m)  [faithful reshape]
            float s  = h * rdotv[ir];
            float mx = halfReduceMax(s);
            float e  = __expf(s - mx);
            float es = halfReduceSum(e);
            o_d = fmaf(t, e / es, o_d);

            // kge: sigmoid(h * dot(r,t)) elementwise over d
            float rt = fullReduceSum(r * t);
            float z  = h * rt;
            kge_acc += 1.f / (1.f + __expf(-z));

            l2_acc = fmaf(h, h, l2_acc);
            l2_acc = fmaf(t, t, l2_acc);
            l2r_acc += rsq[ir];             // uniform across the wave
        }

        // attention logit: a = relu(dot(o, u_hop))
        float a = fullReduceSum(o_d * u[hop * DIM + lane]);
        a = fmaxf(a, 0.f);
        if (lane == 0) a_lds[g] = a;
        o_lds[g][lane] = o_d;
        __syncthreads();

        if (g == 0) {
            float amax = -1e30f;
#pragma unroll
            for (int gg = 0; gg < G; ++gg) amax = fmaxf(amax, a_lds[gg]);
            float wexp[G]; float wsum = 0.f;
#pragma unroll
            for (int gg = 0; gg < G; ++gg) { wexp[gg] = __expf(a_lds[gg] - amax); wsum += wexp[gg]; }
            float inv = 1.f / wsum;
            float oh = 0.f;
#pragma unroll
            for (int gg = 0; gg < G; ++gg) oh = fmaf(o_lds[gg][lane], wexp[gg] * inv, oh);
            y0 += oh;
            if (hop == 1) x1 = v + oh;
        }
        __syncthreads();   // before next hop overwrites a_lds / o_lds
    }

    // block-level scalar reductions
    float kk = fullReduceSum(kge_acc);
    float ll = fullReduceSum(l2_acc);
    if (lane == 0) { red_kge[g] = kk; red_l2[g] = ll + l2r_acc; }
    if (g == 0) y_lds[lane] = y0;
    __syncthreads();

    if (tid == 0) {
        float sk = 0.f, sl = 0.f;
#pragma unroll
        for (int gg = 0; gg < G; ++gg) { sk += red_kge[gg]; sl += red_l2[gg]; }
        atomicAdd(&acc[1], (double)sk);
        atomicAdd(&acc[2], (double)sl);
    }

    if (g == 0) {
        // z_d = sum_e T[d][e] * y[e]   (score = dot(x, T @ y))
        float z = 0.f;
#pragma unroll
        for (int e = 0; e < DIM; ++e) z = fmaf(Tm[lane * DIM + e], y_lds[e], z);
        float score  = fullReduceSum(x1 * z);
        float nv     = ent[(size_t)neg_items[b] * DIM + lane];
        float nscore = fullReduceSum(nv * y0);
        if (lane == 0) {
            float diff = score - nscore;
            // log_sigmoid(diff), numerically stable
            float ls = fminf(diff, 0.f) - log1pf(__expf(-fabsf(diff)));
            atomicAdd(&acc[0], (double)ls);
        }
    }
}

__global__ void kgan_finalize(const double* __restrict__ acc, float* __restrict__ out) {
    double mf  = -acc[0] / (double)BATCH;
    double kge = acc[1] / ((double)BATCH * G * NMEM * DIM);   // sum over hops of per-hop mean
    double l2  = acc[2];
    out[0] = (float)(mf - 0.01 * kge + 1e-5 * l2);
}

extern "C" void kernel_launch(void* const* d_in, const int* in_sizes, int n_in,
                              void* d_out, int out_size, void* d_ws, size_t ws_size,
                              hipStream_t stream) {
    const int*   pos_items = (const int*)d_in[0];
    const int*   neg_items = (const int*)d_in[1];
    const int*   mem_h     = (const int*)d_in[2];
    const int*   mem_r     = (const int*)d_in[3];
    const int*   mem_t     = (const int*)d_in[4];
    const float* ent       = (const float*)d_in[5];
    const float* rel       = (const float*)d_in[6];
    const float* Tm        = (const float*)d_in[7];
    const float* attn_w1   = (const float*)d_in[8];
    const float* attn_w2   = (const float*)d_in[9];

    double* acc = (double*)d_ws;                     // 4 doubles
    float*  u   = (float*)((char*)d_ws + 64);        // 2*64 floats

    kgan_prep<<<1, 128, 0, stream>>>(attn_w1, attn_w2, u, acc);
    kgan_main<<<BATCH, 1024, 0, stream>>>(pos_items, neg_items, mem_h, mem_r, mem_t,
                                          ent, rel, Tm, u, acc);
    kgan_finalize<<<1, 1, 0, stream>>>(acc, (float*)d_out);
}

// Round 2
// 162.750 us; speedup vs baseline: 1.6864x; 1.6864x over previous
//
#include <hip/hip_runtime.h>

// KGAN forward loss on MI355X.
// block = batch row b (1024 blocks x 1024 threads), wave = group g, lane = dim d.
// R2: scalar index loads (s_load), DPP-based reductions (off the LDS pipe),
// no softmax max-subtract (inputs ~0.1-scale), fast rcp, unroll-4.

#define BATCH 1024
#define G     16
#define NMEM  32
#define DIM   64
#define NREL  17

// ---- cross-lane helpers ----------------------------------------------------
// quad_perm xor1 = 0xB1, xor2 = 0x4E; row_ror:4 = 0x124, row_ror:8 = 0x128.
// After xor1+xor2 all quad lanes hold quad-sum; ror4 adds neighbor quad,
// ror8 adds the other pair -> all 16 lanes of a row hold the row sum.
template<int CTRL>
__device__ __forceinline__ float dpp_add(float x) {
    int y = __builtin_amdgcn_update_dpp(0, __float_as_int(x), CTRL, 0xF, 0xF, true);
    return x + __int_as_float(y);
}
template<int OFF>
__device__ __forceinline__ float swz_add(float x) {
    int y = __builtin_amdgcn_ds_swizzle(__float_as_int(x), OFF);
    return x + __int_as_float(y);
}
__device__ __forceinline__ float bperm(int byteidx, float x) {
    return __int_as_float(__builtin_amdgcn_ds_bpermute(byteidx, __float_as_int(x)));
}
// sum over each 32-lane half (all lanes get their half's sum)
__device__ __forceinline__ float red32(float v) {
    v = dpp_add<0xB1>(v);
    v = dpp_add<0x4E>(v);
    v = dpp_add<0x124>(v);
    v = dpp_add<0x128>(v);
    v = swz_add<0x401F>(v);      // xor 16 within 32-lane group
    return v;
}

// ws layout: acc double[4] at offset 0; u float[2*64] at offset 64.
__global__ void kgan_prep(const float* __restrict__ attn_w1,
                          const float* __restrict__ attn_w2,
                          float* __restrict__ u, double* __restrict__ acc) {
    int t = threadIdx.x;            // 0..127
    if (t < 4) acc[t] = 0.0;
    int hop = t >> 6, d = t & 63;
    float s = 0.f;
#pragma unroll
    for (int e = 0; e < DIM; ++e)
        s = fmaf(attn_w1[(hop * DIM + d) * DIM + e], attn_w2[hop * DIM + e], s);
    u[t] = s;
}

__launch_bounds__(1024, 8)
__global__ void kgan_main(const int* __restrict__ pos_items,
                          const int* __restrict__ neg_items,
                          const int* __restrict__ mem_h,
                          const int* __restrict__ mem_r,
                          const int* __restrict__ mem_t,
                          const float* __restrict__ ent,
                          const float* __restrict__ rel,
                          const float* __restrict__ Tm,
                          const float* __restrict__ u,
                          double* __restrict__ acc) {
    const int b    = blockIdx.x;
    const int tid  = threadIdx.x;
    const int lane = tid & 63;
    const int g    = tid >> 6;
    const int gU   = __builtin_amdgcn_readfirstlane(g);   // wave-uniform group id
    const int x32  = (lane ^ 32) << 2;                    // bpermute byte index

    __shared__ float  rel_lds[NREL][DIM];
    __shared__ float2 rv_rs[NREL];        // (rdotv, rsq) interleaved -> ds_read_b64
    __shared__ float  a_lds[G];
    __shared__ float  o_lds[G][DIM];
    __shared__ float  red_k[G];
    __shared__ float  red_l[G];
    __shared__ float  y_lds[DIM];

    for (int i = tid; i < NREL * DIM; i += 1024)
        ((float*)rel_lds)[i] = rel[i];
    const float v = ent[(size_t)pos_items[b] * DIM + lane];
    __syncthreads();

    // per-block precompute: rdotv[r] = dot(rel_r, v); rsq[r] = ||rel_r||^2
    for (int rr = gU; rr < NREL; rr += G) {
        float rd = rel_lds[rr][lane];
        float s1 = red32(rd * v); s1 += bperm(x32, s1);
        float s2 = red32(rd * rd); s2 += bperm(x32, s2);
        if (lane == 0) rv_rs[rr] = make_float2(s1, s2);
    }
    __syncthreads();

    float kge_acc = 0.f, l2_acc = 0.f, l2r_acc = 0.f;
    float y0 = 0.f;   // wave 0: y_d = sum_hop o_h
    float x1 = 0.f;   // wave 0: v + o_h(last hop)

    for (int hop = 0; hop < 2; ++hop) {
        const int base = ((hop * BATCH + b) * G + gU) * NMEM;
        float o_d = 0.f;
#pragma unroll 4
        for (int m = 0; m < NMEM; ++m) {
            const int ih = mem_h[base + m];   // wave-uniform -> s_load
            const int it = mem_t[base + m];
            const int ir = mem_r[base + m];
            const float  h   = ent[(size_t)ih * DIM + lane];
            const float  t   = ent[(size_t)it * DIM + lane];
            const float  r   = rel_lds[ir][lane];
            const float2 rr2 = rv_rs[ir];

            float e = __expf(h * rr2.x);      // softmax numerator (no max: |s|<~0.5)
            float p = r * t;
            // merged butterfly: e needs 32-lane sum, p needs 64-lane sum
            float de = e, dp = p;
            de = dpp_add<0xB1>(de);   dp = dpp_add<0xB1>(dp);
            de = dpp_add<0x4E>(de);   dp = dpp_add<0x4E>(dp);
            de = dpp_add<0x124>(de);  dp = dpp_add<0x124>(dp);
            de = dpp_add<0x128>(de);  dp = dpp_add<0x128>(dp);
            de = swz_add<0x401F>(de); dp = swz_add<0x401F>(dp);
            const float rt = dp + bperm(x32, dp);

            o_d = fmaf(t, e * __builtin_amdgcn_rcpf(de), o_d);

            const float z = h * rt;
            kge_acc += __builtin_amdgcn_rcpf(1.f + __expf(-z));

            l2_acc  = fmaf(h, h, l2_acc);
            l2_acc  = fmaf(t, t, l2_acc);
            l2r_acc += rr2.y;                 // uniform across the wave
        }

        // attention logit: a = relu(dot(o, u_hop))
        float a = red32(o_d * u[hop * DIM + lane]);
        a += bperm(x32, a);
        a = fmaxf(a, 0.f);
        if (lane == 0) a_lds[g] = a;
        o_lds[g][lane] = o_d;
        __syncthreads();

        if (g == 0) {
            float amax = -1e30f;
#pragma unroll
            for (int gg = 0; gg < G; ++gg) amax = fmaxf(amax, a_lds[gg]);
            float wexp[G]; float wsum = 0.f;
#pragma unroll
            for (int gg = 0; gg < G; ++gg) { wexp[gg] = __expf(a_lds[gg] - amax); wsum += wexp[gg]; }
            float inv = 1.f / wsum;
            float oh = 0.f;
#pragma unroll
            for (int gg = 0; gg < G; ++gg) oh = fmaf(o_lds[gg][lane], wexp[gg] * inv, oh);
            y0 += oh;
            if (hop == 1) x1 = v + oh;
        }
        __syncthreads();   // before next hop overwrites a_lds / o_lds
    }

    // block-level scalar reductions
    float kk = red32(kge_acc); kk += bperm(x32, kk);
    float ll = red32(l2_acc);  ll += bperm(x32, ll);
    if (lane == 0) { red_k[g] = kk; red_l[g] = ll + l2r_acc; }
    if (g == 0) y_lds[lane] = y0;
    __syncthreads();

    if (tid == 0) {
        float sk = 0.f, sl = 0.f;
#pragma unroll
        for (int gg = 0; gg < G; ++gg) { sk += red_k[gg]; sl += red_l[gg]; }
        atomicAdd(&acc[1], (double)sk);
        atomicAdd(&acc[2], (double)sl);
    }

    if (g == 0) {
        // z_d = sum_e T[d][e] * y[e]; score = dot(x1, T @ y)
        float z = 0.f;
#pragma unroll
        for (int e = 0; e < DIM; ++e) z = fmaf(Tm[lane * DIM + e], y_lds[e], z);
        float score = red32(x1 * z);  score  += bperm(x32, score);
        float nv    = ent[(size_t)neg_items[b] * DIM + lane];
        float nsc   = red32(nv * y0); nsc    += bperm(x32, nsc);
        if (lane == 0) {
            float diff = score - nsc;
            float ls = fminf(diff, 0.f) - log1pf(__expf(-fabsf(diff)));
            atomicAdd(&acc[0], (double)ls);
        }
    }
}

__global__ void kgan_finalize(const double* __restrict__ acc, float* __restrict__ out) {
    double mf  = -acc[0] / (double)BATCH;
    double kge = acc[1] / ((double)BATCH * G * NMEM * DIM);   // sum of per-hop means
    double l2  = acc[2];
    out[0] = (float)(mf - 0.01 * kge + 1e-5 * l2);
}

extern "C" void kernel_launch(void* const* d_in, const int* in_sizes, int n_in,
                              void* d_out, int out_size, void* d_ws, size_t ws_size,
                              hipStream_t stream) {
    const int*   pos_items = (const int*)d_in[0];
    const int*   neg_items = (const int*)d_in[1];
    const int*   mem_h     = (const int*)d_in[2];
    const int*   mem_r     = (const int*)d_in[3];
    const int*   mem_t     = (const int*)d_in[4];
    const float* ent       = (const float*)d_in[5];
    const float* rel       = (const float*)d_in[6];
    const float* Tm        = (const float*)d_in[7];
    const float* attn_w1   = (const float*)d_in[8];
    const float* attn_w2   = (const float*)d_in[9];

    double* acc = (double*)d_ws;                     // 4 doubles
    float*  u   = (float*)((char*)d_ws + 64);        // 2*64 floats

    kgan_prep<<<1, 128, 0, stream>>>(attn_w1, attn_w2, u, acc);
    kgan_main<<<BATCH, 1024, 0, stream>>>(pos_items, neg_items, mem_h, mem_r, mem_t,
                                          ent, rel, Tm, u, acc);
    kgan_finalize<<<1, 1, 0, stream>>>(acc, (float*)d_out);
}